// Round 1
// 285.804 us; speedup vs baseline: 1.2365x; 1.2365x over previous
//
#include <hip/hip_runtime.h>
#include <cstdint>

typedef _Float16 f16;
typedef __attribute__((ext_vector_type(4))) _Float16 f16x4;
typedef __attribute__((ext_vector_type(8))) _Float16 f16x8;
typedef __attribute__((ext_vector_type(4))) float f32x4;

#define DM   2048
#define TSEQ 2048
#define NB   2
#define NH   16
#define DKH  128
#define LOG2E 1.44269504088896f

__device__ __forceinline__ void gload_lds16(const void* g, void* l) {
  __builtin_amdgcn_global_load_lds((const __attribute__((address_space(1))) void*)g,
                                   (__attribute__((address_space(3))) void*)l, 16, 0, 0);
}

// ---------------- fp32 -> fp16 elementwise ----------------
__global__ __launch_bounds__(256) void cvt_kernel(const float* __restrict__ src,
                                                  f16* __restrict__ dst, int n8) {
  int i = blockIdx.x * 256 + threadIdx.x;
  if (i >= n8) return;
  const float4* s = (const float4*)src + 2 * (size_t)i;
  float4 a = s[0], b = s[1];
  f16x8 o;
  o[0]=(f16)a.x; o[1]=(f16)a.y; o[2]=(f16)a.z; o[3]=(f16)a.w;
  o[4]=(f16)b.x; o[5]=(f16)b.y; o[6]=(f16)b.z; o[7]=(f16)b.w;
  ((f16x8*)dst)[i] = o;
}

// ---------------- W [k][n] fp32 -> Wt [n][k] fp16 (transpose + convert) ----------------
__global__ __launch_bounds__(256) void wt_kernel(const float* __restrict__ W0, const float* __restrict__ W1,
                                                 const float* __restrict__ W2, const float* __restrict__ W3,
                                                 f16* __restrict__ Dqkv, f16* __restrict__ Dout) {
  __shared__ f16 S[64 * 80];
  int z = blockIdx.z;
  const float* W = (z == 0) ? W0 : (z == 1) ? W1 : (z == 2) ? W2 : W3;
  f16* D = (z < 3) ? (Dqkv + (size_t)z * DM * DM) : Dout;
  int n0 = blockIdx.x * 64, k0 = blockIdx.y * 64;
  int tid = threadIdx.x;
#pragma unroll
  for (int i = 0; i < 4; i++) {
    int flat = i * 256 + tid;          // 0..1023 -> 64 rows x 16 float4 cols
    int r = flat >> 4, c4 = flat & 15;
    float4 v = *(const float4*)(W + (size_t)(k0 + r) * DM + n0 + c4 * 4);
    S[(c4 * 4 + 0) * 80 + r] = (f16)v.x;
    S[(c4 * 4 + 1) * 80 + r] = (f16)v.y;
    S[(c4 * 4 + 2) * 80 + r] = (f16)v.z;
    S[(c4 * 4 + 3) * 80 + r] = (f16)v.w;
  }
  __syncthreads();
#pragma unroll
  for (int i = 0; i < 2; i++) {
    int flat = i * 256 + tid;          // 0..511 -> 64 n-rows x 8 chunks
    int nl = flat >> 3, kc = flat & 7;
    f16x8 v = *(const f16x8*)&S[nl * 80 + kc * 8];
    *(f16x8*)(D + (size_t)(n0 + nl) * DM + k0 + kc * 8) = v;
  }
}

// ---------------- GEMM: C[m][n] = sum_k A[m][k]*Bt[n][k] + bias ----------------
// MODE 0: A=xb[4096][2048], Bt=WtQKV[6144][2048] ->
//         Q,K fp16 [B,H,T,Dk]; V fp16 TRANSPOSED [B,H,Dk,T]  (+bias per proj)
// MODE 1: A=AO[4096][2048],  Bt=WtO[2048][2048] -> fp32 d_out [4096][2048] (+bo)
template <int MODE>
__global__ __launch_bounds__(256) void gemm_kernel(const f16* __restrict__ A, const f16* __restrict__ Bt,
                                                   const float* __restrict__ b0, const float* __restrict__ b1,
                                                   const float* __restrict__ b2,
                                                   f16* __restrict__ Oh, float* __restrict__ Of) {
  __shared__ f16 As[128 * 32];
  __shared__ f16 Bs[128 * 32];
  const int K = DM;
  int tid = threadIdx.x, l = tid & 63, w = tid >> 6;
  int wm = w >> 1, wn = w & 1;
  int m0 = blockIdx.y * 128, n0 = blockIdx.x * 128;
  f32x4 acc[4][4] = {};

  for (int kt = 0; kt < K / 32; ++kt) {
    __syncthreads();
#pragma unroll
    for (int i = 0; i < 2; i++) {
      int flat = (w * 2 + i) * 64 + l;     // 0..511
      int row = flat >> 2, c = flat & 3;
      int csw = c ^ (row & 3);             // pre-swizzled source chunk
      gload_lds16(A  + (size_t)(m0 + row) * K + kt * 32 + csw * 8, &As[(w * 2 + i) * 512]);
      gload_lds16(Bt + (size_t)(n0 + row) * K + kt * 32 + csw * 8, &Bs[(w * 2 + i) * 512]);
    }
    __syncthreads();
    f16x8 af[4], bfr[4];
#pragma unroll
    for (int mi = 0; mi < 4; mi++) {
      int row = wm * 64 + mi * 16 + (l & 15);
      int c = (l >> 4) ^ (row & 3);
      af[mi] = *(const f16x8*)&As[row * 32 + c * 8];
    }
#pragma unroll
    for (int ni = 0; ni < 4; ni++) {
      int row = wn * 64 + ni * 16 + (l & 15);
      int c = (l >> 4) ^ (row & 3);
      bfr[ni] = *(const f16x8*)&Bs[row * 32 + c * 8];
    }
#pragma unroll
    for (int mi = 0; mi < 4; mi++)
#pragma unroll
      for (int ni = 0; ni < 4; ni++)
        acc[mi][ni] = __builtin_amdgcn_mfma_f32_16x16x32_f16(af[mi], bfr[ni], acc[mi][ni], 0, 0, 0);
  }

  // epilogue: C layout col = l&15, row = (l>>4)*4 + r
#pragma unroll
  for (int mi = 0; mi < 4; mi++) {
    int gm = m0 + wm * 64 + mi * 16 + ((l >> 4) << 2);
#pragma unroll
    for (int ni = 0; ni < 4; ni++) {
      int gn = n0 + wn * 64 + ni * 16 + (l & 15);
      if (MODE == 0) {
        int proj = gn >> 11, nn = gn & 2047;
        const float* bp = (proj == 0) ? b0 : (proj == 1) ? b1 : b2;
        float bias = bp[nn];
        int h = nn >> 7, d = nn & 127;
        int b = gm >> 11;
        int t0 = gm & 2047;
        if (proj < 2) {
#pragma unroll
          for (int r = 0; r < 4; r++) {
            Oh[(size_t)proj * ((size_t)NB * NH * TSEQ * DKH) +
               (((size_t)(b * NH + h) * TSEQ + t0 + r) * DKH) + d] = (f16)(acc[mi][ni][r] + bias);
          }
        } else {
          // V^T: [B,H,Dk,T] -- 4 consecutive t -> packed 8B store
          f16x4 pk;
#pragma unroll
          for (int r = 0; r < 4; r++) pk[r] = (f16)(acc[mi][ni][r] + bias);
          *(f16x4*)(Oh + 2ull * ((size_t)NB * NH * TSEQ * DKH) +
                    ((size_t)(b * NH + h) * DKH + d) * TSEQ + t0) = pk;
        }
      } else {
        float bias = b0[gn];
#pragma unroll
        for (int r = 0; r < 4; r++)
          Of[(size_t)(gm + r) * DM + gn] = acc[mi][ni][r] + bias;
      }
    }
  }
}

// ---------------- flash attention v2 (swapped-QK^T, in-lane softmax) ----------------
// 512 blocks, 256 threads (4 waves). Block handles 128 q-rows of one (b,h);
// wave w owns 32 q-rows (two 16-row halves). KV tile = 64.
// QK^T computed as mfma(K, Q) so C-layout puts col = q = lo, row = kt:
// each lane holds 16 scores of ONE q-row -> row-reduce is 15 in-lane ops + 2 shuffles
// (vs 4-step butterfly x 8 rows x {max,sum} = 64 bpermutes in the old orientation).
// Defer-max (T13): skip O-rescale unless tile max grows by >THR raw (=8 in log2
// domain after scaling); P bounded by 2^8, safe in f16 store / f32 accum.
__global__ __launch_bounds__(256, 2) void attn_kernel(const f16* __restrict__ Qb, const f16* __restrict__ Kb,
                                                      const f16* __restrict__ Vtb, f16* __restrict__ AO) {
  __shared__ f16 Ks[64 * 128];
  __shared__ f16 Vt[128 * 64];
  __shared__ f16 Ps[4][32 * 72];
  int tid = threadIdx.x, l = tid & 63, w = tid >> 6;
  int lo = l & 15, hi = l >> 4;
  int lin = blockIdx.x;
  int xcd = lin & 7, slot = lin >> 3;
  int bh = xcd * 4 + (slot & 3), qt = slot >> 2;   // bijective: 8 xcd * 4 bh * 16 qt
  const float CSC = 0.12753257f;   // (1/sqrt(128)) * log2(e)
  const float THR = 62.0f;         // raw-score defer threshold: p <= 2^(62*CSC) ~ 2^7.9
  const f16* Qg = Qb + (size_t)bh * TSEQ * DKH;
  const f16* Kg = Kb + (size_t)bh * TSEQ * DKH;
  const f16* Vg = Vtb + (size_t)bh * DKH * TSEQ;   // [Dk][T]

  // Q fragments in registers. As B-operand: col = lo = q-row, k(d) = c*32 + hi*8
  f16x8 aq[2][4];
#pragma unroll
  for (int hf = 0; hf < 2; hf++) {
    int qrow = qt * 128 + w * 32 + hf * 16 + lo;
#pragma unroll
    for (int c = 0; c < 4; c++)
      aq[hf][c] = *(const f16x8*)(Qg + (size_t)qrow * DKH + c * 32 + (hi << 3));
  }

  f32x4 o[2][8] = {};
  float mrow[2] = {-INFINITY, -INFINITY};
  float lrow[2] = {0.f, 0.f};

  for (int ktile = 0; ktile < TSEQ / 64; ++ktile) {
    __syncthreads();
    // stage K [64 kt][128 d]: 16 chunks/row, source chunk pre-swizzled by (row&15)
#pragma unroll
    for (int i = 0; i < 4; i++) {
      int chunk = (w * 4 + i) * 64 + l;
      int rowk = chunk >> 4, c = chunk & 15;
      int csw = c ^ (rowk & 15);
      gload_lds16(Kg + (size_t)(ktile * 64 + rowk) * DKH + csw * 8, &Ks[(w * 4 + i) * 512]);
    }
    // stage V^T [128 d][64 kt]: 8 chunks/row, source chunk pre-swizzled by (d&7)
#pragma unroll
    for (int i = 0; i < 4; i++) {
      int chunk = (w * 4 + i) * 64 + l;
      int d = chunk >> 3, c = chunk & 7;
      int csw = c ^ (d & 7);
      gload_lds16(Vg + (size_t)d * TSEQ + ktile * 64 + csw * 8, &Vt[(w * 4 + i) * 512]);
    }
    __syncthreads();

    // S^T = K Q^T: A = K rows (row=lo -> kt), B = Q (col=lo -> q).
    // Output: col = q = lo, row(reg r, hi) = kt = ks*16 + hi*4 + r.
    f32x4 s[2][4] = {};
    __builtin_amdgcn_s_setprio(1);
#pragma unroll
    for (int ks = 0; ks < 4; ++ks) {
      int ktl = ks * 16 + lo;
#pragma unroll
      for (int c = 0; c < 4; c++) {
        int cc = (c * 4 + hi) ^ lo;   // (ktl&15) == lo
        f16x8 bk = *(const f16x8*)&Ks[ktl * 128 + cc * 8];
        s[0][ks] = __builtin_amdgcn_mfma_f32_16x16x32_f16(bk, aq[0][c], s[0][ks], 0, 0, 0);
        s[1][ks] = __builtin_amdgcn_mfma_f32_16x16x32_f16(bk, aq[1][c], s[1][ks], 0, 0, 0);
      }
    }
    __builtin_amdgcn_s_setprio(0);

    // online softmax, reduction mostly in-lane (lane owns q-row = lo)
#pragma unroll
    for (int hf = 0; hf < 2; hf++) {
      float mk[4];
#pragma unroll
      for (int ks = 0; ks < 4; ks++)
        mk[ks] = fmaxf(fmaxf(s[hf][ks][0], s[hf][ks][1]), fmaxf(s[hf][ks][2], s[hf][ks][3]));
      float mt = fmaxf(fmaxf(mk[0], mk[1]), fmaxf(mk[2], mk[3]));
      mt = fmaxf(mt, __shfl_xor(mt, 16));
      mt = fmaxf(mt, __shfl_xor(mt, 32));   // row max, replicated across hi

      if (__any(mt > mrow[hf] + THR)) {     // wave-uniform; fires ~only on tile 0
        float mn = fmaxf(mrow[hf], mt);
        float al = exp2f((mrow[hf] - mn) * CSC);
        mrow[hf] = mn;
        lrow[hf] *= al;
        // redistribute al from lo-domain to o's (hi,r)-domain
        float alr[4];
#pragma unroll
        for (int r = 0; r < 4; r++) alr[r] = __shfl(al, (hi << 2) + r);
#pragma unroll
        for (int dsub = 0; dsub < 8; dsub++)
#pragma unroll
          for (int r = 0; r < 4; r++) o[hf][dsub][r] *= alr[r];
      }

      float mCn = -mrow[hf] * CSC;
      float sum = 0.f;
#pragma unroll
      for (int ks = 0; ks < 4; ks++) {
        f16x4 pk;
        float part = 0.f;
#pragma unroll
        for (int r = 0; r < 4; r++) {
          float p = exp2f(__builtin_fmaf(s[hf][ks][r], CSC, mCn));
          pk[r] = (f16)p;
          part += p;
        }
        sum += part;
        // P[q][kt]: row = hf*16+lo, col = ks*16 + hi*4 (+r packed) -> 8B store
        *(f16x4*)&Ps[w][(hf * 16 + lo) * 72 + ks * 16 + (hi << 2)] = pk;
      }
      sum += __shfl_xor(sum, 16);
      sum += __shfl_xor(sum, 32);
      lrow[hf] += sum;
    }

    // PV: o[hf][dsub] += P[16x64] * Vt^T[64 x dsub16]; each Vt read feeds 2 MFMAs
    f16x8 pa[2][2];
#pragma unroll
    for (int hf = 0; hf < 2; hf++)
#pragma unroll
      for (int kk = 0; kk < 2; kk++)
        pa[hf][kk] = *(const f16x8*)&Ps[w][(hf * 16 + lo) * 72 + kk * 32 + (hi << 3)];
    __builtin_amdgcn_s_setprio(1);
#pragma unroll
    for (int kk = 0; kk < 2; kk++) {
#pragma unroll
      for (int dsub = 0; dsub < 8; dsub++) {
        int d = dsub * 16 + lo;
        f16x8 vf = *(const f16x8*)&Vt[d * 64 + (((kk * 4 + hi) ^ (d & 7)) << 3)];
        o[0][dsub] = __builtin_amdgcn_mfma_f32_16x16x32_f16(pa[0][kk], vf, o[0][dsub], 0, 0, 0);
        o[1][dsub] = __builtin_amdgcn_mfma_f32_16x16x32_f16(pa[1][kk], vf, o[1][dsub], 0, 0, 0);
      }
    }
    __builtin_amdgcn_s_setprio(0);
  }

  // epilogue: AO[b][t][h*128 + d]; o row = q = hi*4+r, lrow lives in lo-domain
  int b = bh >> 4, h = bh & 15;
#pragma unroll
  for (int hf = 0; hf < 2; hf++) {
    float inv = 1.0f / lrow[hf];
    float invr[4];
#pragma unroll
    for (int r = 0; r < 4; r++) invr[r] = __shfl(inv, (hi << 2) + r);
#pragma unroll
    for (int r = 0; r < 4; r++) {
      int t = qt * 128 + w * 32 + hf * 16 + (hi << 2) + r;
      f16* dst = AO + ((size_t)b * TSEQ + t) * DM + h * DKH;
#pragma unroll
      for (int dsub = 0; dsub < 8; dsub++)
        dst[dsub * 16 + lo] = (f16)(o[hf][dsub][r] * invr[r]);
    }
  }
}

extern "C" void kernel_launch(void* const* d_in, const int* in_sizes, int n_in,
                              void* d_out, int out_size, void* d_ws, size_t ws_size,
                              hipStream_t stream) {
  const float* x  = (const float*)d_in[0];
  const float* Wq = (const float*)d_in[1];
  const float* bq = (const float*)d_in[2];
  const float* Wk = (const float*)d_in[3];
  const float* bk = (const float*)d_in[4];
  const float* Wv = (const float*)d_in[5];
  const float* bv = (const float*)d_in[6];
  const float* Wo = (const float*)d_in[7];
  const float* bo = (const float*)d_in[8];

  f16* ws    = (f16*)d_ws;
  f16* xb    = ws;                      //  8,388,608 elems  [reused as AO]
  f16* WtQKV = ws + 8388608ull;         // 12,582,912
  f16* WtO   = ws + 20971520ull;        //  4,194,304
  f16* Q     = ws + 25165824ull;        //  8,388,608
  f16* Kp    = ws + 33554432ull;        //  8,388,608
  f16* Vp    = ws + 41943040ull;        //  8,388,608  V^T [B,H,Dk,T]
  f16* AO    = xb;

  cvt_kernel<<<4096, 256, 0, stream>>>(x, xb, (NB * TSEQ * DM) / 8);
  wt_kernel<<<dim3(32, 32, 4), 256, 0, stream>>>(Wq, Wk, Wv, Wo, WtQKV, WtO);
  gemm_kernel<0><<<dim3(48, 32), 256, 0, stream>>>(xb, WtQKV, bq, bk, bv, Q, nullptr);
  attn_kernel<<<512, 256, 0, stream>>>(Q, Kp, Vp, AO);
  gemm_kernel<1><<<dim3(16, 32), 256, 0, stream>>>(AO, WtO, bo, nullptr, nullptr, nullptr, (float*)d_out);
}